// Round 11
// baseline (188.270 us; speedup 1.0000x reference)
//
#include <hip/hip_runtime.h>
#include <hip/hip_bf16.h>
#include <stdint.h>

#define Dd 64
#define Hh 8
#define Bb 4
#define Tt 2048
#define NT (Bb * Tt)   // 8192 token rows

typedef __attribute__((ext_vector_type(4))) float f32x4;
typedef __attribute__((ext_vector_type(8))) __bf16 bf16x8;
typedef __attribute__((ext_vector_type(8))) uint16_t u16x8;
typedef __attribute__((ext_vector_type(4))) uint16_t u16x4;

__device__ __forceinline__ uint16_t f2bf_fast(float f) {
    union { __bf16 h; uint16_t u; } c; c.h = (__bf16)f; return c.u;
}
__device__ __forceinline__ uint32_t pkbf(float a, float b) {
    return (uint32_t)f2bf_fast(a) | ((uint32_t)f2bf_fast(b) << 16);
}

// XOR-swizzled layouts; same math for pre-swizzled global copies and reads.
#define SWZ(row, k)   ((row) * 72  + ((k) ^ ((((row) >> 3) & 7) << 3)))   // k<64
#define PSZ(q, k)     ((q)  * 72  + ((k) ^ ((((q)  >> 2) & 3) << 3)))    // 16 q
#define HSZ(q, k)     ((q)  * 264 + ((k) ^ ((((q)  >> 2) & 3) << 3)))    // k<256
#define W2SWZ(col, k) ((col) * 264 + ((k) ^ ((((col) >> 3) & 7) << 3)))  // k<256
#define WPSWZ(col, k) ((col) * 520 + ((k) ^ ((((col) >> 3) & 7) << 3)))  // k<512

#define LOG2E 1.44269504f

// -------------------- K0: one-time conversions into workspace --------------
__global__ __launch_bounds__(256) void setup_kernel(
    const float* __restrict__ x,
    const float* __restrict__ Wq, const float* __restrict__ Wk,
    const float* __restrict__ Wv, const float* __restrict__ Wp,
    const float* __restrict__ W1, const float* __restrict__ W2,
    uint16_t* __restrict__ xb, uint16_t* __restrict__ WtAll,
    uint16_t* __restrict__ WptS, uint16_t* __restrict__ W1g,
    uint16_t* __restrict__ W2g)
{
    const int bid = blockIdx.x, t = threadIdx.x;
    if (bid < 256) {
        size_t base = ((size_t)bid * 256 + t) * 8;
        f32x4 a = *(const f32x4*)&x[base];
        f32x4 b = *(const f32x4*)&x[base + 4];
        u16x8 o;
#pragma unroll
        for (int j = 0; j < 4; ++j) { o[j] = f2bf_fast(a[j]); o[4 + j] = f2bf_fast(b[j]); }
        *(u16x8*)&xb[base] = o;
    } else if (bid < 280) {
        const int mh = bid - 256, m = mh / 8, h = mh % 8;
        const float* W = (m == 0) ? Wq : (m == 1) ? Wk : Wv;
        uint16_t* dst = WtAll + (size_t)mh * 4608;
#pragma unroll
        for (int p = 0; p < 4; ++p) {
            int idx = p * 256 + t;
            int k = idx >> 4, c4 = (idx & 15) * 4;
            f32x4 wv = *(const f32x4*)&W[(size_t)(h * 64 + k) * 64 + c4];
#pragma unroll
            for (int j = 0; j < 4; ++j) dst[SWZ(c4 + j, k)] = f2bf_fast(wv[j]);
        }
    } else if (bid < 288) {
        const int j = bid - 280;
#pragma unroll
        for (int p = 0; p < 16; ++p) {
            int idx = p * 256 + t;
            int col = idx & 63, k = j * 64 + (idx >> 6);
            WptS[WPSWZ(col, k)] = f2bf_fast(Wp[(size_t)k * 64 + col]);
        }
    } else if (bid < 292) {
        const int j = bid - 288;
#pragma unroll
        for (int p = 0; p < 16; ++p) {
            int e = j * 4096 + p * 256 + t;
            int col = e & 255, k = e >> 8;
            W1g[SWZ(col, k)] = f2bf_fast(W1[(size_t)k * 256 + col]);
        }
    } else {
        const int j = bid - 292;
#pragma unroll
        for (int p = 0; p < 16; ++p) {
            int e = j * 4096 + p * 256 + t;
            int col = e & 63, k = e >> 6;
            W2g[W2SWZ(col, k)] = f2bf_fast(W2[(size_t)k * 64 + col]);
        }
    }
}

// -------------------- K1: fused per-head QKV (all 3 mats per block) --------
// Q pre-scaled by log2(e) (exp2-domain attention). V written tile-transposed
// + sigma-permuted (key_store = (w>>1)*32 + g*8 + (w&1)*4 + rr).
__global__ __launch_bounds__(256) void qkv_kernel(
    const uint16_t* __restrict__ xb, const uint16_t* __restrict__ WtAll,
    const float* __restrict__ bq, const float* __restrict__ bk,
    const float* __restrict__ bv,
    uint16_t* __restrict__ qb, uint16_t* __restrict__ kb, uint16_t* __restrict__ vb)
{
    __shared__ uint16_t WtF[3][64 * 72];
    const int rt = blockIdx.x, h = blockIdx.y;
    const int t = threadIdx.x, lane = t & 63, w = t >> 6;
    const int l15 = lane & 15, g = lane >> 4;

#pragma unroll
    for (int m = 0; m < 3; ++m) {
        const u16x8* src = (const u16x8*)(WtAll + (size_t)(m * 8 + h) * 4608);
        u16x8* dst = (u16x8*)WtF[m];
        dst[t] = src[t];
        dst[256 + t] = src[256 + t];
        if (t < 64) dst[512 + t] = src[512 + t];
    }
    const int row = rt * 64 + w * 16 + l15;
    bf16x8 a0 = *(const bf16x8*)&xb[(size_t)row * 64 + g * 8];
    bf16x8 a1 = *(const bf16x8*)&xb[(size_t)row * 64 + 32 + g * 8];
    __syncthreads();

#pragma unroll
    for (int m = 0; m < 3; ++m) {
        const float* bias = (m == 0) ? bq : (m == 1) ? bk : bv;
        f32x4 acc[4] = {};
#pragma unroll
        for (int ct = 0; ct < 4; ++ct) {
            bf16x8 b0 = *(const bf16x8*)&WtF[m][SWZ(ct * 16 + l15, g * 8)];
            bf16x8 b1 = *(const bf16x8*)&WtF[m][SWZ(ct * 16 + l15, 32 + g * 8)];
            acc[ct] = __builtin_amdgcn_mfma_f32_16x16x32_bf16(a0, b0, acc[ct], 0, 0, 0);
            acc[ct] = __builtin_amdgcn_mfma_f32_16x16x32_bf16(a1, b1, acc[ct], 0, 0, 0);
        }
        if (m < 2) {
            uint16_t* out = (m == 0) ? qb : kb;
            const float scl = (m == 0) ? LOG2E : 1.0f;
#pragma unroll
            for (int ct = 0; ct < 4; ++ct) {
                float bb = bias[h * 64 + ct * 16 + l15];
#pragma unroll
                for (int rr = 0; rr < 4; ++rr) {
                    int orow = rt * 64 + w * 16 + g * 4 + rr;
                    out[((size_t)h * NT + orow) * 64 + ct * 16 + l15] =
                        f2bf_fast((acc[ct][rr] + bb) * scl);
                }
            }
        } else {
            const size_t tb = ((size_t)h * NT + (size_t)rt * 64) * 64;
            const int kcol = (w >> 1) * 32 + g * 8 + (w & 1) * 4;  // sigma-inv
#pragma unroll
            for (int ct = 0; ct < 4; ++ct) {
                float bb = bias[h * 64 + ct * 16 + l15];
                u16x4 vo;
#pragma unroll
                for (int rr = 0; rr < 4; ++rr) vo[rr] = f2bf_fast(acc[ct][rr] + bb);
                *(u16x4*)&vb[tb + (size_t)(ct * 16 + l15) * 64 + kcol] = vo;
            }
        }
    }
}

// -------------------- K2: flash attention (8 waves, 128-row q-tiles) -------
// 512 blocks x 512 threads; one q-tile per block, nkv = 2qt+2 (big-first per
// XCD). 16 waves/CU = 4/SIMD -- doubles latency hiding vs r10. One K/V
// staging serves 128 q-rows: 1 K + 1 V u16x8 slot per thread.
__global__ __launch_bounds__(512) void attn_kernel9(
    const uint16_t* __restrict__ qb, const uint16_t* __restrict__ kb,
    const uint16_t* __restrict__ vb, uint16_t* __restrict__ cat)
{
    __shared__ uint16_t KsF[2][64 * 72];   // K [key][d], swizzled
    __shared__ uint16_t VtF[2][64 * 72];   // V^T [d][key_sigma], swizzled
    const int bid = blockIdx.x;
    const int lbid = (bid & 7) * 64 + (bid >> 3);   // XCD swizzle, 512%8==0
    const int qt = 15 - (lbid & 15);                // big tiles dispatch first
    const int hb = lbid >> 4;
    const int h = hb & 7, b = hb >> 3;
    const int t = threadIdx.x, lane = t & 63, w = t >> 6;   // w in 0..7
    const int l15 = lane & 15, g = lane >> 4;
    const size_t base = ((size_t)h * NT + (size_t)b * Tt) * 64;
    const uint16_t* Qh  = qb + base;
    const uint16_t* Kh  = kb + base;
    const uint16_t* VhT = vb + base;   // + kv*4096 + d*64 + key_sigma

    union { uint32_t u[4]; bf16x8 v; } onesu;
#pragma unroll
    for (int j = 0; j < 4; ++j) onesu.u[j] = 0x3F803F80u;   // bf16 1.0 x2
    const bf16x8 ones = onesu.v;

    const int qlocal = w * 16 + l15;                // 0..127 within tile
    bf16x8 aq0, aq1;
    {
        int qrow = qt * 128 + qlocal;
        aq0 = *(const bf16x8*)&Qh[(size_t)qrow * 64 + g * 8];
        aq1 = *(const bf16x8*)&Qh[(size_t)qrow * 64 + 32 + g * 8];
    }
    f32x4 o[4] = {};                // O[q=g*4+rj][d=dt*16+l15]
    f32x4 l_acc = {};               // l[q=g*4+rj]
    float m_run = -INFINITY;        // per-lane q = l15 (log2 domain)

    // prologue: stage kv=0 (1 K-slot + 1 V-slot per thread)
    {
        int r = t >> 3, c8 = (t & 7) * 8;
        size_t off = (size_t)r * 64 + c8;
        u16x8 kk = *(const u16x8*)&Kh[off];
        u16x8 vv = *(const u16x8*)&VhT[off];
        *(u16x8*)&KsF[0][SWZ(r, c8)] = kk;
        *(u16x8*)&VtF[0][SWZ(r, c8)] = vv;
    }
    __syncthreads();

    const int nkv = 2 * qt + 2;
    for (int kv = 0; kv < nkv; ++kv) {
        const int cur = kv & 1;
        const bool pf = (kv + 1) < nkv;
        u16x8 pK, pV;
        if (pf) {
            size_t off = (size_t)(kv + 1) * 4096 + (size_t)(t >> 3) * 64 + (t & 7) * 8;
            pK = *(const u16x8*)&Kh[off];
            pV = *(const u16x8*)&VhT[off];
        }
        // S^T = K Q : s[kt][rj] = S[key=kt*16+g*4+rj][q=l15] (log2 domain)
        f32x4 s[4];
#pragma unroll
        for (int kt = 0; kt < 4; ++kt) {
            bf16x8 bk0 = *(const bf16x8*)&KsF[cur][SWZ(kt * 16 + l15, g * 8)];
            bf16x8 bk1 = *(const bf16x8*)&KsF[cur][SWZ(kt * 16 + l15, 32 + g * 8)];
            f32x4 z = {};
            z = __builtin_amdgcn_mfma_f32_16x16x32_bf16(bk0, aq0, z, 0, 0, 0);
            z = __builtin_amdgcn_mfma_f32_16x16x32_bf16(bk1, aq1, z, 0, 0, 0);
            s[kt] = z;
        }
        // causal mask: only the last two kv tiles intersect the diagonal
        if (kv >= 2 * qt) {
            const int koff = (kv - 2 * qt) * 64;
#pragma unroll
            for (int kt = 0; kt < 4; ++kt)
#pragma unroll
                for (int rj = 0; rj < 4; ++rj)
                    if (koff + kt * 16 + g * 4 + rj > qlocal) s[kt][rj] = -INFINITY;
        }
        // row max
        float mt = fmaxf(fmaxf(fmaxf(s[0][0], s[0][1]), fmaxf(s[0][2], s[0][3])),
                         fmaxf(fmaxf(s[1][0], s[1][1]), fmaxf(s[1][2], s[1][3])));
        mt = fmaxf(mt, fmaxf(fmaxf(fmaxf(s[2][0], s[2][1]), fmaxf(s[2][2], s[2][3])),
                             fmaxf(fmaxf(s[3][0], s[3][1]), fmaxf(s[3][2], s[3][3]))));
        mt = fmaxf(mt, __shfl_xor(mt, 16));
        mt = fmaxf(mt, __shfl_xor(mt, 32));
        // defer-max (T13), threshold 8*log2e
        if (__any((int)(mt > m_run + 11.5409f))) {
            float mnew = fmaxf(m_run, mt);
            float alpha = exp2f(m_run - mnew);
            m_run = mnew;
            float a0 = __shfl(alpha, g * 4 + 0);
            float a1 = __shfl(alpha, g * 4 + 1);
            float a2 = __shfl(alpha, g * 4 + 2);
            float a3 = __shfl(alpha, g * 4 + 3);
            l_acc[0] *= a0; l_acc[1] *= a1; l_acc[2] *= a2; l_acc[3] *= a3;
#pragma unroll
            for (int dt = 0; dt < 4; ++dt) {
                o[dt][0] *= a0; o[dt][1] *= a1; o[dt][2] *= a2; o[dt][3] *= a3;
            }
        }
        // P = 2^(s - m)
#pragma unroll
        for (int kt = 0; kt < 4; ++kt)
#pragma unroll
            for (int rj = 0; rj < 4; ++rj)
                s[kt][rj] = exp2f(s[kt][rj] - m_run);
        // pack P (lane-local, sigma slot order)
        union { uint32_t wd[4]; bf16x8 v; } ap0, ap1;
        ap0.wd[0] = pkbf(s[0][0], s[0][1]); ap0.wd[1] = pkbf(s[0][2], s[0][3]);
        ap0.wd[2] = pkbf(s[1][0], s[1][1]); ap0.wd[3] = pkbf(s[1][2], s[1][3]);
        ap1.wd[0] = pkbf(s[2][0], s[2][1]); ap1.wd[1] = pkbf(s[2][2], s[2][3]);
        ap1.wd[2] = pkbf(s[3][0], s[3][1]); ap1.wd[3] = pkbf(s[3][2], s[3][3]);
        // O += P V ; l += P ones
#pragma unroll
        for (int c = 0; c < 2; ++c) {
            const bf16x8 ap = c ? ap1.v : ap0.v;
            l_acc = __builtin_amdgcn_mfma_f32_16x16x32_bf16(ap, ones, l_acc, 0, 0, 0);
#pragma unroll
            for (int dt = 0; dt < 4; ++dt) {
                bf16x8 bv = *(const bf16x8*)&VtF[cur][SWZ(dt * 16 + l15, c * 32 + g * 8)];
                o[dt] = __builtin_amdgcn_mfma_f32_16x16x32_bf16(ap, bv, o[dt], 0, 0, 0);
            }
        }
        if (pf) {
            int r = t >> 3, c8 = (t & 7) * 8;
            *(u16x8*)&KsF[cur ^ 1][SWZ(r, c8)] = pK;
            *(u16x8*)&VtF[cur ^ 1][SWZ(r, c8)] = pV;
            __syncthreads();
        }
    }
    // epilogue: inv already in O's layout -- no shuffles
    f32x4 inv;
#pragma unroll
    for (int rj = 0; rj < 4; ++rj) inv[rj] = 1.f / l_acc[rj];
#pragma unroll
    for (int dt = 0; dt < 4; ++dt) {
        int rowb = qt * 128 + w * 16 + g * 4;
        size_t cb = ((size_t)b * Tt + rowb) * 512 + h * 64 + dt * 16 + l15;
        cat[cb]        = f2bf_fast(o[dt][0] * inv[0]);
        cat[cb + 512]  = f2bf_fast(o[dt][1] * inv[1]);
        cat[cb + 1024] = f2bf_fast(o[dt][2] * inv[2]);
        cat[cb + 1536] = f2bf_fast(o[dt][3] * inv[3]);
    }
}

// -------------------- K3: fused proj+LN1+FFN+LN2 -> out --------------------
__global__ __launch_bounds__(128) void tail_kernel(
    const uint16_t* __restrict__ cat, const uint16_t* __restrict__ WptS,
    const uint16_t* __restrict__ W1g, const uint16_t* __restrict__ W2g,
    const float* __restrict__ bp, const float* __restrict__ b1,
    const float* __restrict__ b2, const float* __restrict__ x,
    const float* __restrict__ g1, const float* __restrict__ be1,
    const float* __restrict__ g2, const float* __restrict__ be2,
    float* __restrict__ out)
{
    __shared__ uint16_t h1S[2][16 * 72];
    __shared__ uint16_t hidS[2][16 * 264];
    const int rt = blockIdx.x;
    const int t = threadIdx.x, lane = t & 63, w = t >> 6;
    const int l15 = lane & 15, g = lane >> 4;
    const int arow = rt * 32 + w * 16 + l15;

    f32x4 acc[4] = {};
#pragma unroll
    for (int kt = 0; kt < 16; ++kt) {
        bf16x8 a = *(const bf16x8*)&cat[(size_t)arow * 512 + kt * 32 + g * 8];
#pragma unroll
        for (int ct = 0; ct < 4; ++ct) {
            bf16x8 bfr = *(const bf16x8*)&WptS[WPSWZ(ct * 16 + l15, kt * 32 + g * 8)];
            acc[ct] = __builtin_amdgcn_mfma_f32_16x16x32_bf16(a, bfr, acc[ct], 0, 0, 0);
        }
    }
    float bpv[4], g1v[4], b1v[4];
#pragma unroll
    for (int ct = 0; ct < 4; ++ct) {
        bpv[ct] = bp[ct * 16 + l15];
        g1v[ct] = g1[ct * 16 + l15];
        b1v[ct] = be1[ct * 16 + l15];
    }
    float hv[4][4];
#pragma unroll
    for (int rr = 0; rr < 4; ++rr) {
        int drow = rt * 32 + w * 16 + g * 4 + rr;
        float s[4], sum = 0.f;
#pragma unroll
        for (int ct = 0; ct < 4; ++ct) {
            s[ct] = acc[ct][rr] + bpv[ct] + x[(size_t)drow * 64 + ct * 16 + l15];
            sum += s[ct];
        }
        sum += __shfl_xor(sum, 1); sum += __shfl_xor(sum, 2);
        sum += __shfl_xor(sum, 4); sum += __shfl_xor(sum, 8);
        float mu = sum * (1.f / 64.f);
        float v = 0.f;
#pragma unroll
        for (int ct = 0; ct < 4; ++ct) { s[ct] -= mu; v += s[ct] * s[ct]; }
        v += __shfl_xor(v, 1); v += __shfl_xor(v, 2);
        v += __shfl_xor(v, 4); v += __shfl_xor(v, 8);
        float rstd = rsqrtf(v * (1.f / 64.f) + 1e-5f);
#pragma unroll
        for (int ct = 0; ct < 4; ++ct) {
            float h = s[ct] * rstd * g1v[ct] + b1v[ct];
            hv[ct][rr] = h;
            h1S[w][PSZ(g * 4 + rr, ct * 16 + l15)] = f2bf_fast(h);
        }
    }
    bf16x8 ha0 = *(const bf16x8*)&h1S[w][PSZ(l15, g * 8)];
    bf16x8 ha1 = *(const bf16x8*)&h1S[w][PSZ(l15, 32 + g * 8)];
#pragma unroll
    for (int nt = 0; nt < 16; ++nt) {
        f32x4 a1c = {};
        bf16x8 w10 = *(const bf16x8*)&W1g[SWZ(nt * 16 + l15, g * 8)];
        bf16x8 w11 = *(const bf16x8*)&W1g[SWZ(nt * 16 + l15, 32 + g * 8)];
        a1c = __builtin_amdgcn_mfma_f32_16x16x32_bf16(ha0, w10, a1c, 0, 0, 0);
        a1c = __builtin_amdgcn_mfma_f32_16x16x32_bf16(ha1, w11, a1c, 0, 0, 0);
        float bb1 = b1[nt * 16 + l15];
#pragma unroll
        for (int rr = 0; rr < 4; ++rr)
            hidS[w][HSZ(g * 4 + rr, nt * 16 + l15)] =
                f2bf_fast(fmaxf(a1c[rr] + bb1, 0.f));
    }
    f32x4 acc2[4] = {};
#pragma unroll
    for (int ks = 0; ks < 8; ++ks) {
        bf16x8 hfr = *(const bf16x8*)&hidS[w][HSZ(l15, ks * 32 + g * 8)];
#pragma unroll
        for (int ct = 0; ct < 4; ++ct) {
            bf16x8 w2f = *(const bf16x8*)&W2g[W2SWZ(ct * 16 + l15, ks * 32 + g * 8)];
            acc2[ct] = __builtin_amdgcn_mfma_f32_16x16x32_bf16(hfr, w2f, acc2[ct], 0, 0, 0);
        }
    }
    float b2v[4], g2v[4], be2v[4];
#pragma unroll
    for (int ct = 0; ct < 4; ++ct) {
        b2v[ct]  = b2[ct * 16 + l15];
        g2v[ct]  = g2[ct * 16 + l15];
        be2v[ct] = be2[ct * 16 + l15];
    }
#pragma unroll
    for (int rr = 0; rr < 4; ++rr) {
        int drow = rt * 32 + w * 16 + g * 4 + rr;
        float s[4], sum = 0.f;
#pragma unroll
        for (int ct = 0; ct < 4; ++ct) {
            s[ct] = acc2[ct][rr] + b2v[ct] + hv[ct][rr];
            sum += s[ct];
        }
        sum += __shfl_xor(sum, 1); sum += __shfl_xor(sum, 2);
        sum += __shfl_xor(sum, 4); sum += __shfl_xor(sum, 8);
        float mu = sum * (1.f / 64.f);
        float v = 0.f;
#pragma unroll
        for (int ct = 0; ct < 4; ++ct) { s[ct] -= mu; v += s[ct] * s[ct]; }
        v += __shfl_xor(v, 1); v += __shfl_xor(v, 2);
        v += __shfl_xor(v, 4); v += __shfl_xor(v, 8);
        float rstd = rsqrtf(v * (1.f / 64.f) + 1e-5f);
#pragma unroll
        for (int ct = 0; ct < 4; ++ct)
            out[(size_t)drow * 64 + ct * 16 + l15] =
                s[ct] * rstd * g2v[ct] + be2v[ct];
    }
}

// ---------------------------------------------------------------------------
extern "C" void kernel_launch(void* const* d_in, const int* in_sizes, int n_in,
                              void* d_out, int out_size, void* d_ws, size_t ws_size,
                              hipStream_t stream)
{
    (void)in_sizes; (void)n_in; (void)out_size; (void)ws_size;
    const float* x   = (const float*)d_in[0];
    const float* Wq  = (const float*)d_in[1];
    const float* bq  = (const float*)d_in[2];
    const float* Wk  = (const float*)d_in[3];
    const float* bk  = (const float*)d_in[4];
    const float* Wv  = (const float*)d_in[5];
    const float* bv  = (const float*)d_in[6];
    const float* Wp  = (const float*)d_in[7];
    const float* bp  = (const float*)d_in[8];
    const float* W1  = (const float*)d_in[9];
    const float* b1  = (const float*)d_in[10];
    const float* W2  = (const float*)d_in[11];
    const float* b2  = (const float*)d_in[12];
    const float* g1  = (const float*)d_in[13];
    const float* be1 = (const float*)d_in[14];
    const float* g2  = (const float*)d_in[15];
    const float* be2 = (const float*)d_in[16];
    float* outp = (float*)d_out;

    char* w = (char*)d_ws;
    uint16_t* qb   = (uint16_t*)w;                      // [H][NT][64] 8MB
    uint16_t* kb   = qb + (size_t)Hh * NT * 64;         // 8MB
    uint16_t* vb   = kb + (size_t)Hh * NT * 64;         // 8MB (tile-T, sigma)
    uint16_t* cat  = vb + (size_t)Hh * NT * 64;         // [NT][512] 8MB
    uint16_t* WptS = cat + (size_t)NT * 512;            // 33280 u16
    uint16_t* W1g  = WptS + 33280;                      // 18432 u16
    uint16_t* W2g  = W1g + 18432;                       // 16896 u16
    uint16_t* xb   = W2g + 16896;                       // [NT][64] 1MB
    uint16_t* WtAll= xb + (size_t)NT * 64;              // 24*4608 u16

    setup_kernel<<<dim3(296), dim3(256), 0, stream>>>(
        x, Wq, Wk, Wv, Wp, W1, W2, xb, WtAll, WptS, W1g, W2g);
    qkv_kernel<<<dim3(NT / 64, Hh), dim3(256), 0, stream>>>(
        xb, WtAll, bq, bk, bv, qb, kb, vb);
    attn_kernel9<<<dim3(512), dim3(512), 0, stream>>>(qb, kb, vb, cat);
    tail_kernel<<<dim3(256), dim3(128), 0, stream>>>(
        cat, WptS, W1g, W2g, bp, b1, b2, x, g1, be1, g2, be2, outp);
}